// Round 9
// baseline (294.942 us; speedup 1.0000x reference)
//
#include <hip/hip_runtime.h>
#include <hip/hip_bf16.h>
#include <math.h>

// B=4, L=S=2048, H=8, E=64, T=1.0.  I/O fp32.
// Pipeline: tr_fwd -> fft_fwd -> qkpack -> flash_mfma -> fft_inv -> out_tr.
// R9: flash restructured: 128-thread blocks (2 waves), 32 x-rows per wave
// (two 16-row MFMA A-sets) -> each K/V B-frag read feeds 2x the MFMA work,
// halving LDS-read + staging + loop cost per row. Grid/swizzle unchanged.
#define LOGN  11
#define NN    2048
#define LOGM  10
#define MM    1024
#define NF    1025
#define NYP   1056         // NF padded to 33 tiles of 32 (pads zeroed)
#define TWO_PI 6.283185307179586f
#define INV_SQRT_N 0.022097086912079608f      // 1/sqrt(2048)
#define INV_SCALE  0.044194173824159216f      // 2/sqrt(2048)  (M*z -> out)

typedef __attribute__((ext_vector_type(8))) short bhalf8;
typedef __attribute__((ext_vector_type(4))) float f32x4;

#define MFMA16(a, b, c) __builtin_amdgcn_mfma_f32_16x16x32_bf16(a, b, c, 0, 0, 0)

__device__ __forceinline__ unsigned short f2bf(float f) {
    union { float f; unsigned u; } v; v.f = f;
    unsigned r = v.u + 0x7FFFu + ((v.u >> 16) & 1u);   // RNE
    return (unsigned short)(r >> 16);
}
__device__ __forceinline__ float bf2f(unsigned short h) {
    union { unsigned u; float f; } v; v.u = ((unsigned)h) << 16;
    return v.f;
}

// ---------------------------------------------------------------------------
// 1024-pt complex DIT stages in LDS (input pre-bit-reversed).
// ---------------------------------------------------------------------------
__device__ __forceinline__ void fft_stages_m(float2* buf, const float2* tw, int tid)
{
    for (int st = 1; st <= LOGM; st++) {
        int half = 1 << (st - 1);
        #pragma unroll
        for (int it = 0; it < 2; it++) {
            int j   = tid + 256 * it;          // 512 butterflies
            int pos = j & (half - 1);
            int grp = j >> (st - 1);
            int i0  = (grp << st) + pos;
            int i1  = i0 + half;
            float2 w = tw[pos << (LOGM - st)];
            float2 a = buf[i0];
            float2 b = buf[i1];
            float2 bw = make_float2(b.x * w.x - b.y * w.y,
                                    b.x * w.y + b.y * w.x);
            buf[i0] = make_float2(a.x + bw.x, a.y + bw.y);
            buf[i1] = make_float2(a.x - bw.x, a.y - bw.y);
        }
        __syncthreads();
    }
}

// ---------------------------------------------------------------------------
// Input transpose: in[b][t][h][e] fp32 -> ttr[(tensor*32+bh)*64+e][t] bf16.
// ---------------------------------------------------------------------------
__global__ __launch_bounds__(256) void tr_fwd(const float* __restrict__ q,
                                              const float* __restrict__ k,
                                              const float* __restrict__ v,
                                              unsigned short* __restrict__ ttr)
{
    __shared__ float Ts[64][65];
    int tt     = blockIdx.x;          // t-tile 0..31
    int h      = blockIdx.y;          // 0..7
    int z      = blockIdx.z;          // tensor*4 + b
    int tensor = z >> 2;
    int b      = z & 3;
    int tid    = threadIdx.x;
    int t0     = tt * 64;

    const float* in = (tensor == 0) ? q : (tensor == 1) ? k : v;

    {
        int tl = tid >> 2, ec = (tid & 3) * 16;
        const float* src = in + ((size_t)b * 2048 + t0 + tl) * 512 + h * 64 + ec;
        #pragma unroll
        for (int m = 0; m < 4; m++) {
            float4 v4 = *(const float4*)(src + m * 4);
            Ts[tl][ec + m * 4 + 0] = v4.x;
            Ts[tl][ec + m * 4 + 1] = v4.y;
            Ts[tl][ec + m * 4 + 2] = v4.z;
            Ts[tl][ec + m * 4 + 3] = v4.w;
        }
    }
    __syncthreads();
    {
        int el = tid >> 2, tc = (tid & 3) * 16;
        size_t row = ((size_t)(tensor * 32 + b * 8 + h)) * 64 + el;
        unsigned short* dst = ttr + row * 2048 + t0 + tc;
        #pragma unroll
        for (int j = 0; j < 16; j++) dst[j] = f2bf(Ts[tc + j][el]);
    }
}

// ---------------------------------------------------------------------------
// Forward rFFT (ortho) via real-packing, contiguous bf16 series input.
// Output bf16 planes P[bh*128+kk][1056]. Grid: g = e*96 + (tensor*32+bh).
// ---------------------------------------------------------------------------
__global__ __launch_bounds__(256) void fft_fwd(const unsigned short* __restrict__ ttr,
                                               unsigned short* __restrict__ Pq,
                                               unsigned short* __restrict__ Pk,
                                               unsigned short* __restrict__ Pv)
{
    __shared__ float2 buf[MM];
    __shared__ float2 tw[MM / 2];

    int g      = blockIdx.x;
    int p      = g % 96;              // tensor*32 + bh
    int e      = g / 96;              // 0..63
    int tensor = p / 32;
    int bh     = p % 32;
    int tid    = threadIdx.x;

    unsigned short* plane = (tensor == 0) ? Pq : (tensor == 1) ? Pk : Pv;

    for (int i = tid; i < MM / 2; i += 256) {
        float ang = -TWO_PI * (float)i / (float)MM;
        float sv, cv;
        __sincosf(ang, &sv, &cv);
        tw[i] = make_float2(cv, sv);
    }

    const unsigned short* src = ttr + ((size_t)p * 64 + e) * 2048;
    #pragma unroll
    for (int i = 0; i < 4; i++) {
        int j = tid + 256 * i;
        unsigned pr = *(const unsigned*)(src + 2 * j);   // x[2j], x[2j+1]
        float x0 = bf2f((unsigned short)(pr & 0xFFFFu));
        float x1 = bf2f((unsigned short)(pr >> 16));
        buf[__brev((unsigned)j) >> (32 - LOGM)] = make_float2(x0, x1);
    }
    __syncthreads();

    fft_stages_m(buf, tw, tid);

    unsigned short* dre = plane + ((size_t)bh * 128 + e) * NYP;
    unsigned short* dim_ = dre + (size_t)64 * NYP;

    for (int kk = tid; kk < NF; kk += 256) {
        float2 A  = buf[kk & (MM - 1)];
        float2 Bc = buf[(MM - kk) & (MM - 1)];
        float Ex = 0.5f * (A.x + Bc.x), Ey = 0.5f * (A.y - Bc.y);
        float Dx = 0.5f * (A.x - Bc.x), Dy = 0.5f * (A.y + Bc.y);
        float Ox = Dy, Oy = -Dx;                    // D / i
        float th = -(TWO_PI / (float)NN) * (float)kk;
        float sn, cs;
        __sincosf(th, &sn, &cs);
        float Xr = Ex + cs * Ox - sn * Oy;
        float Xi = Ey + cs * Oy + sn * Ox;
        dre[kk]  = f2bf(Xr * INV_SQRT_N);
        dim_[kk] = f2bf(Xi * INV_SQRT_N);
    }
    for (int y = NF + tid; y < NYP; y += 256) { dre[y] = 0; dim_[y] = 0; }
}

// ---------------------------------------------------------------------------
// Transpose q,k planes [bh*128+kk][1056] -> [bh][1056][128] for MFMA staging.
// ---------------------------------------------------------------------------
__global__ __launch_bounds__(256) void qkpack(const unsigned short* __restrict__ Pq,
                                              const unsigned short* __restrict__ Pk,
                                              unsigned short* __restrict__ Qp,
                                              unsigned short* __restrict__ Kp)
{
    __shared__ unsigned short Ts[32][136];
    int y0  = blockIdx.x * 32;
    int bh  = blockIdx.y;
    int tsr = blockIdx.z;
    int tid = threadIdx.x;

    const unsigned short* srcp = (tsr == 0) ? Pq : Pk;
    unsigned short* dstp       = (tsr == 0) ? Qp : Kp;

    {
        int kk = tid >> 1, seg = tid & 1;
        const unsigned short* sp = srcp + ((size_t)bh * 128 + kk) * NYP + y0 + seg * 16;
        #pragma unroll
        for (int j = 0; j < 16; j++) Ts[seg * 16 + j][kk] = sp[j];
    }
    __syncthreads();
    {
        int y = tid >> 3, c = tid & 7;
        unsigned short* dst = dstp + ((size_t)bh * NYP + y0 + y) * 128 + c * 16;
        #pragma unroll
        for (int j = 0; j < 16; j++) dst[j] = Ts[y][c * 16 + j];
    }
}

// ---------------------------------------------------------------------------
// MFMA flash attention, no-max softmax, y-split x2.
// R9: 128 threads / 2 waves; each wave owns 32 x-rows as two 16-row A-sets
// -> every K B-frag feeds 4 MFMA (re/im x 2 sets), every V B-frag feeds 2.
// XCD swizzle (g = idx*32 + bh) + register prefetch of next K/V tile.
// numb layout: [half][bh][kk=0..127][x=0..1055] bf16, x contiguous.
// ---------------------------------------------------------------------------
struct FlashShared {
    union {
        struct {
            unsigned short Ks[32][136];
            unsigned short Vs[128][40];
        } kv;                                  // 18944 B
        unsigned short OutT[128][72];          // 18432 B  (epilogue only)
    } u;
    unsigned short Ps[2][32][40];              // per-wave P (32 rows x 32 y)
};

__global__ __launch_bounds__(128) void flash_mfma(
    const unsigned short* __restrict__ Qp,   // [bh][1056][128] bf16
    const unsigned short* __restrict__ Kp,   // [bh][1056][128] bf16
    const unsigned short* __restrict__ Vt,   // [bh*128+kk][1056] bf16
    unsigned short* __restrict__ numb,       // [2][bh][128][1056] bf16
    float* __restrict__ lbuf)                // [2][bh*1056+x] fp32
{
    __shared__ FlashShared S;

    int g    = blockIdx.x;            // idx*32 + bh : g%8 == bh%8 (XCD pin)
    int bh   = g & 31;
    int idx  = g >> 5;                // 0..33
    int half = idx / 17;
    int x0   = (idx % 17) * 64;
    int tid  = threadIdx.x;           // 0..127
    int w    = tid >> 6;              // wave 0..1
    int lane = tid & 63;
    int qd   = lane >> 4;
    int col  = lane & 15;

    // ---- Q A-fragments: 2 sets of 16 rows per wave ----
    bhalf8 Are[2][4];                 // [set][ks]  (Aim: ks<2 -> Are[s][ks+2])
    bhalf8 Aneg[2][2];                // [set][ks]  = -Are[s][ks] (for im, ks>=2)
    #pragma unroll
    for (int s = 0; s < 2; s++) {
        int xq = min(x0 + w * 32 + s * 16 + col, 1024);
        const unsigned short* qb = Qp + ((size_t)bh * NYP + xq) * 128 + qd * 8;
        #pragma unroll
        for (int ks = 0; ks < 4; ks++) Are[s][ks] = *(const bhalf8*)(qb + ks * 32);
        #pragma unroll
        for (int ks = 0; ks < 2; ks++) {
            bhalf8 t = Are[s][ks];
            unsigned* u = (unsigned*)&t;
            #pragma unroll
            for (int j = 0; j < 4; j++) u[j] ^= 0x80008000u;
            Aneg[s][ks] = t;
        }
    }

    f32x4 O[2][8];
    #pragma unroll
    for (int s = 0; s < 2; s++)
        #pragma unroll
        for (int n = 0; n < 8; n++) O[s][n] = (f32x4){0.f, 0.f, 0.f, 0.f};
    float Lacc[2][4] = {{0.f, 0.f, 0.f, 0.f}, {0.f, 0.f, 0.f, 0.f}};

    const unsigned short* kpb = Kp + (size_t)bh * NYP * 128;
    const unsigned short* vtb = Vt + (size_t)bh * 128 * NYP;

    // staging: instruction-major 16B chunks (perfect wave coalescing)
    // K tile 32x128 shorts = 512 chunks: f = m*128+tid, row f>>4, col (f&15)*8
    // V tile 128x32 shorts = 512 chunks: f = m*128+tid, row f>>2, col (f&3)*8
    int krow[4], vrow[4];
    #pragma unroll
    for (int m = 0; m < 4; m++) {
        krow[m] = (m * 128 + tid) >> 4;
        vrow[m] = (m * 128 + tid) >> 2;
    }
    int kcol = (tid & 15) * 8, vcol = (tid & 3) * 8;

    int yt0 = half * 17, yt1 = min(33, yt0 + 17);

    uint4 kc[4], vc[4];
    #pragma unroll
    for (int m = 0; m < 4; m++) {
        kc[m] = *(const uint4*)(kpb + ((size_t)(yt0 * 32 + krow[m])) * 128 + kcol);
        vc[m] = *(const uint4*)(vtb + (size_t)vrow[m] * NYP + yt0 * 32 + vcol);
    }

    for (int yt = yt0; yt < yt1; yt++) {
        __syncthreads();                   // prev tile LDS reads done
        #pragma unroll
        for (int m = 0; m < 4; m++) {
            *(uint4*)&S.u.kv.Ks[krow[m]][kcol] = kc[m];
            *(uint4*)&S.u.kv.Vs[vrow[m]][vcol] = vc[m];
        }
        __syncthreads();

        // ---- issue next tile's global loads (overlap with compute) ----
        if (yt + 1 < yt1) {
            int y0n = (yt + 1) * 32;
            #pragma unroll
            for (int m = 0; m < 4; m++) {
                kc[m] = *(const uint4*)(kpb + ((size_t)(y0n + krow[m])) * 128 + kcol);
                vc[m] = *(const uint4*)(vtb + (size_t)vrow[m] * NYP + y0n + vcol);
            }
        }

        // ---- QK: 32 rows x 32 cols per wave ----
        f32x4 sre[2][2], sim[2][2];       // [set][sc]
        #pragma unroll
        for (int s = 0; s < 2; s++)
            #pragma unroll
            for (int sc = 0; sc < 2; sc++) {
                sre[s][sc] = (f32x4){0.f, 0.f, 0.f, 0.f};
                sim[s][sc] = (f32x4){0.f, 0.f, 0.f, 0.f};
            }
        #pragma unroll
        for (int sc = 0; sc < 2; sc++)
            #pragma unroll
            for (int ks = 0; ks < 4; ks++) {
                bhalf8 bfrag = *(const bhalf8*)&S.u.kv.Ks[col + 16 * sc][ks * 32 + qd * 8];
                #pragma unroll
                for (int s = 0; s < 2; s++) {
                    sre[s][sc] = MFMA16(Are[s][ks], bfrag, sre[s][sc]);
                    bhalf8 ai = (ks < 2) ? Are[s][ks + 2] : Aneg[s][ks - 2];
                    sim[s][sc] = MFMA16(ai, bfrag, sim[s][sc]);
                }
            }

        // ---- p = exp(|s|/8), lazy l ----
        #pragma unroll
        for (int s = 0; s < 2; s++)
            #pragma unroll
            for (int r = 0; r < 4; r++) {
                float re0 = sre[s][0][r], im0 = sim[s][0][r];
                float re1 = sre[s][1][r], im1 = sim[s][1][r];
                float p0 = __expf(0.125f * sqrtf(re0 * re0 + im0 * im0));
                float p1 = __expf(0.125f * sqrtf(re1 * re1 + im1 * im1));
                Lacc[s][r] += p0 + p1;
                S.Ps[w][s * 16 + qd * 4 + r][col]      = f2bf(p0);
                S.Ps[w][s * 16 + qd * 4 + r][col + 16] = f2bf(p1);
            }

        // ---- PV: O[32 x 128] += P[32 x 32] . V[32 x 128] ----
        bhalf8 pa0 = *(const bhalf8*)&S.Ps[w][col][qd * 8];
        bhalf8 pa1 = *(const bhalf8*)&S.Ps[w][16 + col][qd * 8];
        #pragma unroll
        for (int n = 0; n < 8; n++) {
            bhalf8 bv = *(const bhalf8*)&S.u.kv.Vs[n * 16 + col][qd * 8];
            O[0][n] = MFMA16(pa0, bv, O[0][n]);
            O[1][n] = MFMA16(pa1, bv, O[1][n]);
        }
    }

    // ---- l reduce + store ----
    size_t hofs = (size_t)half * 32 * NYP;
    #pragma unroll
    for (int s = 0; s < 2; s++)
        #pragma unroll
        for (int r = 0; r < 4; r++) {
            float ls = Lacc[s][r];
            ls += __shfl_xor(ls, 1);
            ls += __shfl_xor(ls, 2);
            ls += __shfl_xor(ls, 4);
            ls += __shfl_xor(ls, 8);
            if (half == 1) ls -= 31.0f;    // zero-pad columns contributed 1 each
            int x = x0 + w * 32 + s * 16 + qd * 4 + r;
            if (x <= 1024 && col == 0) lbuf[hofs + (size_t)bh * NYP + x] = ls;
        }

    // ---- numerator: C-layout -> LDS overlay -> coalesced row writes ----
    __syncthreads();                       // Ks/Vs dead; safe to overlay
    #pragma unroll
    for (int s = 0; s < 2; s++)
        #pragma unroll
        for (int r = 0; r < 4; r++)
            #pragma unroll
            for (int n = 0; n < 8; n++)
                S.u.OutT[n * 16 + col][w * 32 + s * 16 + qd * 4 + r] = f2bf(O[s][n][r]);
    __syncthreads();
    {
        int kk2 = tid;                     // 0..127
        unsigned short* dst =
            numb + (((size_t)half * 32 + bh) * 128 + kk2) * NYP + x0;
        #pragma unroll
        for (int seg = 0; seg < 4; seg++) {
            int cx = seg * 16;
            if (x0 + cx < NYP) {
                *(uint4*)(dst + cx)     = *(const uint4*)&S.u.OutT[kk2][cx];
                *(uint4*)(dst + cx + 8) = *(const uint4*)&S.u.OutT[kk2][cx + 8];
            }
        }
    }
}

// ---------------------------------------------------------------------------
// Inverse rFFT (ortho): combine halves (coalesced bf16 reads), packed irFFT,
// write contiguous staging st[bh*64+e][2048] fp32.
// ---------------------------------------------------------------------------
__global__ __launch_bounds__(256) void fft_inv(const unsigned short* __restrict__ numb,
                                               const float* __restrict__ lbuf,
                                               float* __restrict__ st)
{
    __shared__ float2 buf[MM];
    __shared__ float2 tw[MM / 2];

    int s   = blockIdx.x;          // bh*64 + e
    int e   = s & 63;
    int bh  = s >> 6;
    int tid = threadIdx.x;

    for (int i = tid; i < MM / 2; i += 256) {
        float ang = TWO_PI * (float)i / (float)MM;
        float sv, cv;
        __sincosf(ang, &sv, &cv);
        tw[i] = make_float2(cv, sv);
    }

    const size_t HS = (size_t)32 * 128 * NYP;
    const unsigned short* nbr = numb + ((size_t)bh * 128 + e) * NYP;
    const unsigned short* nbi = numb + ((size_t)bh * 128 + 64 + e) * NYP;
    const float* l0 = lbuf + (size_t)bh * NYP;
    const float* l1 = l0 + (size_t)32 * NYP;

    #pragma unroll
    for (int i = 0; i < 4; i++) {
        int kk = tid + 256 * i;
        int x1 = kk, x2 = 1024 - kk;
        float iv1 = 1.f / (l0[x1] + l1[x1]);
        float iv2 = 1.f / (l0[x2] + l1[x2]);
        float Ax = (bf2f(nbr[x1]) + bf2f(nbr[HS + x1])) * iv1;
        float Ay = (bf2f(nbi[x1]) + bf2f(nbi[HS + x1])) * iv1;
        float Bx = (bf2f(nbr[x2]) + bf2f(nbr[HS + x2])) * iv2;
        float By = -((bf2f(nbi[x2]) + bf2f(nbi[HS + x2])) * iv2);
        float Ex = 0.5f * (Ax + Bx), Ey = 0.5f * (Ay + By);
        float Dx = 0.5f * (Ax - Bx), Dy = 0.5f * (Ay - By);
        float th = (TWO_PI / (float)NN) * (float)kk;
        float sn, cs;
        __sincosf(th, &sn, &cs);
        float Ox = Dx * cs - Dy * sn;
        float Oy = Dx * sn + Dy * cs;
        buf[__brev((unsigned)kk) >> (32 - LOGM)] = make_float2(Ex - Oy, Ey + Ox);
    }
    __syncthreads();

    fft_stages_m(buf, tw, tid);

    float* dst = st + ((size_t)bh * 64 + e) * 2048;
    #pragma unroll
    for (int i = 0; i < 4; i++) {
        int j = tid + 256 * i;
        float2 z = buf[j];
        *(float2*)&dst[2 * j] = make_float2(z.x * INV_SCALE, z.y * INV_SCALE);
    }
}

// ---------------------------------------------------------------------------
// Final transpose: st[bh*64+e][t] -> out[b][t][h][e].  64x64 tiles via LDS.
// ---------------------------------------------------------------------------
__global__ __launch_bounds__(256) void out_tr(const float* __restrict__ st,
                                              float* __restrict__ out)
{
    __shared__ float Ts[64][65];
    int tt  = blockIdx.x;         // t-tile 0..31
    int h   = blockIdx.y;         // 0..7
    int b   = blockIdx.z;         // 0..3
    int tid = threadIdx.x;
    int bh  = b * 8 + h;

    {
        int e = tid >> 2, tc = (tid & 3) * 16;
        const float* src = st + ((size_t)bh * 64 + e) * 2048 + tt * 64 + tc;
        #pragma unroll
        for (int m = 0; m < 4; m++) {
            float4 v4 = *(const float4*)(src + m * 4);
            Ts[e][tc + m * 4 + 0] = v4.x;
            Ts[e][tc + m * 4 + 1] = v4.y;
            Ts[e][tc + m * 4 + 2] = v4.z;
            Ts[e][tc + m * 4 + 3] = v4.w;
        }
    }
    __syncthreads();
    {
        int t = tid >> 2, ec = (tid & 3) * 16;
        float* dst = out + (size_t)b * 2048 * 512 + (size_t)(tt * 64 + t) * 512
                     + h * 64 + ec;
        #pragma unroll
        for (int m = 0; m < 4; m++) {
            float4 v4;
            v4.x = Ts[ec + m * 4 + 0][t];
            v4.y = Ts[ec + m * 4 + 1][t];
            v4.z = Ts[ec + m * 4 + 2][t];
            v4.w = Ts[ec + m * 4 + 3][t];
            *(float4*)(dst + m * 4) = v4;
        }
    }
}

// ---------------------------------------------------------------------------
extern "C" void kernel_launch(void* const* d_in, const int* in_sizes, int n_in,
                              void* d_out, int out_size, void* d_ws, size_t ws_size,
                              hipStream_t stream)
{
    const float* q = (const float*)d_in[0];
    const float* k = (const float*)d_in[1];
    const float* v = (const float*)d_in[2];
    float* out = (float*)d_out;

    char* ws = (char*)d_ws;
    const size_t PL = (size_t)32 * 128 * NYP * sizeof(unsigned short); // 8.65 MB
    unsigned short* Pq = (unsigned short*)(ws);
    unsigned short* Pk = (unsigned short*)(ws + PL);
    unsigned short* Pv = (unsigned short*)(ws + 2 * PL);
    // ttr at 3PL (25.9 MB); dead after fft_fwd, then Qp/Kp reuse the space.
    unsigned short* ttr = (unsigned short*)(ws + 3 * PL);
    unsigned short* Qp = (unsigned short*)(ws + 3 * PL);
    unsigned short* Kp = (unsigned short*)(ws + 4 * PL);
    // numb aliases Pq+Pk (dead after qkpack): 2*PL exactly.
    unsigned short* numb = (unsigned short*)(ws);
    // st aliases Qp+Kp (dead after flash_mfma): 16.78 MB <= 2*PL.
    float* st   = (float*)(ws + 3 * PL);
    float* lbuf = (float*)(ws + 5 * PL);          // 270 KB; peak ws 51.9 MB

    hipLaunchKernelGGL(tr_fwd, dim3(32, 8, 12), dim3(256), 0, stream,
                       q, k, v, ttr);
    hipLaunchKernelGGL(fft_fwd, dim3(3 * 2048), dim3(256), 0, stream,
                       ttr, Pq, Pk, Pv);
    hipLaunchKernelGGL(qkpack, dim3(33, 32, 2), dim3(256), 0, stream,
                       Pq, Pk, Qp, Kp);
    hipLaunchKernelGGL(flash_mfma, dim3(1088), dim3(128), 0, stream,
                       Qp, Kp, Pv, numb, lbuf);
    hipLaunchKernelGGL(fft_inv, dim3(2048), dim3(256), 0, stream,
                       numb, lbuf, st);
    hipLaunchKernelGGL(out_tr, dim3(32, 8, 4), dim3(256), 0, stream,
                       st, out);
}